// Round 7
// baseline (463.902 us; speedup 1.0000x reference)
//
#include <hip/hip_runtime.h>
#include <math.h>

typedef unsigned int uint;

#define N_ITEMS 7000
#define N_NODES 37000
#define N_USERS 30000
#define DIM     128
#define HD      64        // DIM/2, dims handled as packed bf16 pairs
#define NREL    10
#define NBASES  8
#define BATCH   512
#define CTXL    100
#define E_MAX   400000

// ---- workspace layout (4-byte element offsets) ----
#define OFF_CNT    0                               // N_USERS*NREL ints
#define OFF_ICNT   (OFF_CNT + N_USERS * NREL)      // N_ITEMS ints
#define OFF_UCNT   (OFF_ICNT + N_ITEMS)            // N_USERS ints
#define ZERO_ELEMS (OFF_UCNT + N_USERS)            // zero up to here (~1.35 MB)
#define OFF_ICUR   ZERO_ELEMS                      // N_ITEMS ints
#define OFF_UCUR   (OFF_ICUR + N_ITEMS)            // N_USERS ints
#define OFF_ICSR   (OFF_UCUR + N_USERS)            // E ints (user idx grouped by item)
#define OFF_UCSR   (OFF_ICSR + E_MAX)              // E ints (s | rel<<16 grouped by user)
#define OFF_WC     (OFF_UCSR + E_MAX)              // NREL*N_ITEMS*HD uints (bf16x2)
#define OFF_ACC    (OFF_WC + NREL * N_ITEMS * HD)  // N_USERS*HD uints (bf16x2)
#define OFF_MEAN   (OFF_ACC + N_USERS * HD)        // N_ITEMS*HD uints (bf16x2)
#define OFF_SCORE  (OFF_MEAN + N_ITEMS * HD)       // N_ITEMS floats

// ---------------- bf16 pack/unpack (RNE) ----------------
__device__ __forceinline__ float2 bf2f(uint p) {
  float2 r;
  r.x = __uint_as_float(p << 16);
  r.y = __uint_as_float(p & 0xffff0000u);
  return r;
}
__device__ __forceinline__ uint f2bf(float x, float y) {
  uint a = __float_as_uint(x), b = __float_as_uint(y);
  a += 0x7fffu + ((a >> 16) & 1u);
  b += 0x7fffu + ((b >> 16) & 1u);
  return (a >> 16) | (b & 0xffff0000u);
}

// ---------------- wave reductions ----------------
__device__ __forceinline__ float wave_sum(float v) {
#pragma unroll
  for (int o = 1; o < 64; o <<= 1) v += __shfl_xor(v, o, 64);
  return v;
}
__device__ __forceinline__ float wave_max(float v) {
#pragma unroll
  for (int o = 1; o < 64; o <<= 1) v = fmaxf(v, __shfl_xor(v, o, 64));
  return v;
}

// ---------------- kernel 1: combine (blocks [0,1750)) U count (rest) ----------------
#define COMBINE_BLOCKS (N_ITEMS / 4)   // 1750, 4 items per 256-thread block
__global__ __launch_bounds__(256) void k_initcomb(const float* __restrict__ basis,
                                                  const float* __restrict__ comp,
                                                  uint* __restrict__ Wc,
                                                  const int* __restrict__ ei,
                                                  const int* __restrict__ et, int E,
                                                  int* __restrict__ cnt,
                                                  int* __restrict__ icnt,
                                                  int* __restrict__ ucnt) {
  int tid = threadIdx.x;
  if (blockIdx.x < COMBINE_BLOCKS) {
    int i = blockIdx.x * 4 + (tid >> 6);
    int lane = tid & 63;
    float2 bb[NBASES];
#pragma unroll
    for (int b = 0; b < NBASES; ++b)
      bb[b] = ((const float2*)basis)[((size_t)b * N_NODES + i) * HD + lane];
#pragma unroll
    for (int r = 0; r < NREL; ++r) {
      float sx = 0.f, sy = 0.f;
#pragma unroll
      for (int b = 0; b < NBASES; ++b) {
        float c = comp[r * NBASES + b];
        sx = fmaf(c, bb[b].x, sx);
        sy = fmaf(c, bb[b].y, sy);
      }
      Wc[((size_t)r * N_ITEMS + i) * HD + lane] = f2bf(sx, sy);
    }
  } else {
    int e = (blockIdx.x - COMBINE_BLOCKS) * 256 + tid;
    if (e < E) {
      int s  = ei[e];
      int u0 = ei[E + e] - N_ITEMS;
      int t  = et[e];
      atomicAdd(&cnt[u0 * NREL + t], 1);
      atomicAdd(&icnt[s], 1);
      atomicAdd(&ucnt[u0], 1);
    }
  }
}

// ---------------- kernel 2: exclusive scans -> cursors ----------------
__global__ __launch_bounds__(1024) void k_scan(const int* __restrict__ icnt,
                                               const int* __restrict__ ucnt,
                                               int* __restrict__ icur,
                                               int* __restrict__ ucur) {
  __shared__ int ss[1024];
  const int* in;
  int n;
  int* cur;
  if (blockIdx.x == 0) { in = icnt; n = N_ITEMS; cur = icur; }
  else                 { in = ucnt; n = N_USERS; cur = ucur; }
  int t = threadIdx.x;
  int chunk = (n + 1023) / 1024;
  int lo = t * chunk, hi = lo + chunk;
  if (lo > n) lo = n;
  if (hi > n) hi = n;
  int s = 0;
  for (int i = lo; i < hi; ++i) s += in[i];
  ss[t] = s;
  __syncthreads();
  for (int o = 1; o < 1024; o <<= 1) {
    int v = (t >= o) ? ss[t - o] : 0;
    __syncthreads();
    ss[t] += v;
    __syncthreads();
  }
  int base = (t > 0) ? ss[t - 1] : 0;
  for (int i = lo; i < hi; ++i) { cur[i] = base; base += in[i]; }
}

// ---------------- kernel 3: fill CSR payloads ----------------
__global__ __launch_bounds__(256) void k_fill(const int* __restrict__ ei,
                                              const int* __restrict__ et, int E,
                                              int* __restrict__ icur,
                                              int* __restrict__ ucur,
                                              int* __restrict__ icsr,
                                              int* __restrict__ ucsr) {
  int e = blockIdx.x * 256 + threadIdx.x;
  if (e >= E) return;
  int s = ei[e];
  int u0 = ei[E + e] - N_ITEMS;
  int t = et[e];
  icsr[atomicAdd(&icur[s], 1)] = u0;
  ucsr[atomicAdd(&ucur[u0], 1)] = s | (t << 16);
}

// ---------------- kernel 4: per-user aggregate (4 users per 256-thread block) ---------
__global__ __launch_bounds__(256) void k_useragg(const int* __restrict__ ucnt,
                                                 const int* __restrict__ ucur,
                                                 const int* __restrict__ ucsr,
                                                 const int* __restrict__ cnt,
                                                 const uint* __restrict__ Wc,
                                                 const float* __restrict__ root,
                                                 uint* __restrict__ acc) {
  int u = blockIdx.x * 4 + (threadIdx.x >> 6);
  int lane = threadIdx.x & 63;
  int deg = ucnt[u];
  int base = ucur[u] - deg;   // cursor ended at segment end
  float wl = 0.f;
  if (lane < NREL) {
    int c = cnt[u * NREL + lane];
    wl = (c > 0) ? 1.0f / (float)c : 0.0f;   // lanes >= NREL stay 0 (pad relies on it)
  }
  float2 av[8];
#pragma unroll
  for (int k = 0; k < 8; ++k) { av[k].x = 0.f; av[k].y = 0.f; }
  for (int j0 = 0; j0 < deg; j0 += 64) {
    int m = deg - j0;
    if (m > 64) m = 64;
    int pl = (lane < m) ? ucsr[base + j0 + lane] : 0;
    for (int kk = 0; kk < m; kk += 16) {
#pragma unroll
      for (int k = 0; k < 16; ++k) {
        int idx = kk + k;                 // wave-uniform
        int p = __shfl(pl, idx & 63);
        int r = p >> 16;
        float w = (idx < m) ? __shfl(wl, r) : 0.f;   // pad: weight 0
        uint q = Wc[(size_t)(r * N_ITEMS + (p & 0xffff)) * HD + lane];
        float2 f = bf2f(q);
        av[k & 7].x = fmaf(w, f.x, av[k & 7].x);
        av[k & 7].y = fmaf(w, f.y, av[k & 7].y);
      }
    }
  }
  float2 rt = ((const float2*)root)[(size_t)(N_ITEMS + u) * HD + lane];
  rt.x += ((av[0].x + av[1].x) + (av[2].x + av[3].x)) +
          ((av[4].x + av[5].x) + (av[6].x + av[7].x));
  rt.y += ((av[0].y + av[1].y) + (av[2].y + av[3].y)) +
          ((av[4].y + av[5].y) + (av[6].y + av[7].y));
  acc[(size_t)u * HD + lane] = f2bf(rt.x, rt.y);
}

// ---------------- kernel 5: per-item aggregate (4 items per block) + mean + logit ------
__global__ __launch_bounds__(256) void k_itemagg(const int* __restrict__ icnt,
                                                 const int* __restrict__ icur,
                                                 const int* __restrict__ icsr,
                                                 const uint* __restrict__ acc,
                                                 const float* __restrict__ bias,
                                                 const float* __restrict__ attn_a,
                                                 const float* __restrict__ attn_b,
                                                 uint* __restrict__ mean,
                                                 float* __restrict__ score) {
  int i = blockIdx.x * 4 + (threadIdx.x >> 6);
  int lane = threadIdx.x & 63;
  int deg = icnt[i];
  int base = icur[i] - deg;
  float2 av[8];
#pragma unroll
  for (int k = 0; k < 8; ++k) { av[k].x = 0.f; av[k].y = 0.f; }
  for (int j0 = 0; j0 < deg; j0 += 64) {
    int m = deg - j0;
    if (m > 64) m = 64;
    int pl = (lane < m) ? icsr[base + j0 + lane] : 0;
    for (int kk = 0; kk < m; kk += 16) {
#pragma unroll
      for (int k = 0; k < 16; ++k) {
        int idx = kk + k;                 // wave-uniform
        int u0 = __shfl(pl, idx & 63);
        uint q = acc[(size_t)u0 * HD + lane];
        float2 f = bf2f(q);
        if (idx < m) {                    // uniform predicate; pad contributes 0
          av[k & 7].x += f.x;
          av[k & 7].y += f.y;
        }
      }
    }
  }
  float sx = ((av[0].x + av[1].x) + (av[2].x + av[3].x)) +
             ((av[4].x + av[5].x) + (av[6].x + av[7].x));
  float sy = ((av[0].y + av[1].y) + (av[2].y + av[3].y)) +
             ((av[4].y + av[5].y) + (av[6].y + av[7].y));
  float2 mv = {0.f, 0.f};
  if (deg > 0) {
    float inv = 1.0f / (float)deg;
    float2 bv = ((const float2*)bias)[lane];
    mv.x = sx * inv + bv.x;
    mv.y = sy * inv + bv.y;
  }
  mean[(size_t)i * HD + lane] = f2bf(mv.x, mv.y);
  float z0 = 0.f, z1 = 0.f;
#pragma unroll 8
  for (int k2 = 0; k2 < HD; ++k2) {
    float hx = __shfl(mv.x, k2);
    float hy = __shfl(mv.y, k2);
    float2 w0 = ((const float2*)attn_a)[(size_t)(2 * k2) * HD + lane];
    float2 w1 = ((const float2*)attn_a)[(size_t)(2 * k2 + 1) * HD + lane];
    z0 = fmaf(hx, w0.x, z0); z1 = fmaf(hx, w0.y, z1);
    z0 = fmaf(hy, w1.x, z0); z1 = fmaf(hy, w1.y, z1);
  }
  float2 ab = ((const float2*)attn_b)[lane];
  float v = wave_sum(tanhf(z0) * ab.x + tanhf(z1) * ab.y);
  if (lane == 0) score[i] = (deg > 0) ? v : -1e9f;
}

// ---------------- kernel 6: pool + fc1 + fc2 + profile (2 samples per block) ----------
__global__ __launch_bounds__(256) void k_batch2(const int* __restrict__ ctx0,
                                                const int* __restrict__ ctx1,
                                                const uint* __restrict__ mean,
                                                const float* __restrict__ score,
                                                const float* __restrict__ fc1_w,
                                                const float* __restrict__ fc1_b,
                                                const float* __restrict__ fc2_w,
                                                const float* __restrict__ fc2_b,
                                                const float* __restrict__ efc1_w,
                                                const float* __restrict__ efc1_b,
                                                const float* __restrict__ efc2_w,
                                                const float* __restrict__ efc2_b,
                                                float* __restrict__ out) {
  __shared__ float2 shp[2][2][HD];   // [sample in block][side][dim-pair]
  int sb = threadIdx.x >> 7;         // sample within block (0/1)
  int b = blockIdx.x * 2 + sb;
  int wv = (threadIdx.x >> 6) & 1;   // side: 0 = init, 1 = resp
  int lane = threadIdx.x & 63;
  float2* out2 = (float2*)out;

  // ---- side wv: softmax over ctx, pool, fc1, fc2 (shfl-only within the wave) ----
  const int* cx = (wv ? ctx1 : ctx0) + (size_t)b * CTXL;
  int id0 = cx[lane];
  float e0 = (id0 >= 0) ? score[id0] : -1e9f;
  int id1 = -1;
  float e1 = -3.0e38f;
  if (lane < CTXL - 64) {
    id1 = cx[64 + lane];
    e1 = (id1 >= 0) ? score[id1] : -1e9f;
  }
  float mx = wave_max(fmaxf(e0, e1));
  float x0 = expf(e0 - mx);
  float x1 = (lane < CTXL - 64) ? expf(e1 - mx) : 0.f;
  float inv = 1.0f / wave_sum(x0 + x1);
  float w0 = (id0 >= 0) ? x0 * inv : 0.f;
  float w1 = (id1 >= 0) ? x1 * inv : 0.f;
  int i0 = (id0 >= 0) ? id0 : 0;
  int i1 = (id1 >= 0) ? id1 : 0;

  float2 av[4];
#pragma unroll
  for (int k = 0; k < 4; ++k) { av[k].x = 0.f; av[k].y = 0.f; }
  for (int j = 0; j < 64; j += 4) {
#pragma unroll
    for (int k = 0; k < 4; ++k) {
      int ii = __shfl(i0, j + k);
      float ww = __shfl(w0, j + k);
      float2 f = bf2f(mean[(size_t)ii * HD + lane]);
      av[k].x = fmaf(ww, f.x, av[k].x);
      av[k].y = fmaf(ww, f.y, av[k].y);
    }
  }
  for (int j = 0; j < CTXL - 64; j += 4) {
#pragma unroll
    for (int k = 0; k < 4; ++k) {
      int ii = __shfl(i1, j + k);
      float ww = __shfl(w1, j + k);
      float2 f = bf2f(mean[(size_t)ii * HD + lane]);
      av[k].x = fmaf(ww, f.x, av[k].x);
      av[k].y = fmaf(ww, f.y, av[k].y);
    }
  }
  float2 pool;
  pool.x = (av[0].x + av[1].x) + (av[2].x + av[3].x);
  pool.y = (av[0].y + av[1].y) + (av[2].y + av[3].y);

  float2 z = ((const float2*)fc1_b)[lane];
#pragma unroll 8
  for (int k2 = 0; k2 < HD; ++k2) {
    float hx = __shfl(pool.x, k2);
    float hy = __shfl(pool.y, k2);
    float2 wa = ((const float2*)fc1_w)[(size_t)(2 * k2) * HD + lane];
    float2 wb = ((const float2*)fc1_w)[(size_t)(2 * k2 + 1) * HD + lane];
    z.x = fmaf(hx, wa.x, z.x); z.y = fmaf(hx, wa.y, z.y);
    z.x = fmaf(hy, wb.x, z.x); z.y = fmaf(hy, wb.y, z.y);
  }
  z.x = fmaxf(z.x, 0.f);
  z.y = fmaxf(z.y, 0.f);

  float2 z2 = ((const float2*)fc2_b)[lane];
#pragma unroll 8
  for (int k2 = 0; k2 < HD; ++k2) {
    float hx = __shfl(z.x, k2);
    float hy = __shfl(z.y, k2);
    float2 wa = ((const float2*)fc2_w)[(size_t)(2 * k2) * HD + lane];
    float2 wb = ((const float2*)fc2_w)[(size_t)(2 * k2 + 1) * HD + lane];
    z2.x = fmaf(hx, wa.x, z2.x); z2.y = fmaf(hx, wa.y, z2.y);
    z2.x = fmaf(hy, wb.x, z2.x); z2.y = fmaf(hy, wb.y, z2.y);
  }
  z2.x = fmaxf(z2.x, 0.f);
  z2.y = fmaxf(z2.y, 0.f);
  out2[((size_t)(1 + wv) * BATCH + b) * HD + lane] = z2;   // p_init / p_resp
  shp[sb][wv][lane] = z2;
  __syncthreads();

  // ---- profile = project(concat(p_init, p_resp)) on side-0 wave of each sample ----
  if (wv == 0) {
    float2 p0 = shp[sb][0][lane];
    float2 p1 = shp[sb][1][lane];
    float2 zz = ((const float2*)efc1_b)[lane];
#pragma unroll 8
    for (int k2 = 0; k2 < HD; ++k2) {
      float hx = __shfl(p0.x, k2);
      float hy = __shfl(p0.y, k2);
      float2 wa = ((const float2*)efc1_w)[(size_t)(2 * k2) * HD + lane];
      float2 wb = ((const float2*)efc1_w)[(size_t)(2 * k2 + 1) * HD + lane];
      zz.x = fmaf(hx, wa.x, zz.x); zz.y = fmaf(hx, wa.y, zz.y);
      zz.x = fmaf(hy, wb.x, zz.x); zz.y = fmaf(hy, wb.y, zz.y);
    }
#pragma unroll 8
    for (int k2 = 0; k2 < HD; ++k2) {
      float hx = __shfl(p1.x, k2);
      float hy = __shfl(p1.y, k2);
      float2 wa = ((const float2*)efc1_w)[(size_t)(DIM + 2 * k2) * HD + lane];
      float2 wb = ((const float2*)efc1_w)[(size_t)(DIM + 2 * k2 + 1) * HD + lane];
      zz.x = fmaf(hx, wa.x, zz.x); zz.y = fmaf(hx, wa.y, zz.y);
      zz.x = fmaf(hy, wb.x, zz.x); zz.y = fmaf(hy, wb.y, zz.y);
    }
    zz.x = fmaxf(zz.x, 0.f);
    zz.y = fmaxf(zz.y, 0.f);

    float2 zf = ((const float2*)efc2_b)[lane];
#pragma unroll 8
    for (int k2 = 0; k2 < HD; ++k2) {
      float hx = __shfl(zz.x, k2);
      float hy = __shfl(zz.y, k2);
      float2 wa = ((const float2*)efc2_w)[(size_t)(2 * k2) * HD + lane];
      float2 wb = ((const float2*)efc2_w)[(size_t)(2 * k2 + 1) * HD + lane];
      zf.x = fmaf(hx, wa.x, zf.x); zf.y = fmaf(hx, wa.y, zf.y);
      zf.x = fmaf(hy, wb.x, zf.x); zf.y = fmaf(hy, wb.y, zf.y);
    }
    zf.x = fmaxf(zf.x, 0.f);
    zf.y = fmaxf(zf.y, 0.f);
    out2[(size_t)b * HD + lane] = zf;   // profile
  }
}

// ---------------- launcher ----------------
extern "C" void kernel_launch(void* const* d_in, const int* in_sizes, int n_in,
                              void* d_out, int out_size, void* d_ws, size_t ws_size,
                              hipStream_t stream) {
  const int*   ei     = (const int*)d_in[0];
  const int*   et     = (const int*)d_in[1];
  const int*   ctx0   = (const int*)d_in[2];
  const int*   ctx1   = (const int*)d_in[3];
  const float* basis  = (const float*)d_in[4];
  const float* comp   = (const float*)d_in[5];
  const float* root   = (const float*)d_in[6];
  const float* bias   = (const float*)d_in[7];
  const float* attn_a = (const float*)d_in[8];
  const float* attn_b = (const float*)d_in[9];
  const float* fc1_w  = (const float*)d_in[10];
  const float* fc1_b  = (const float*)d_in[11];
  const float* fc2_w  = (const float*)d_in[12];
  const float* fc2_b  = (const float*)d_in[13];
  const float* efc1_w = (const float*)d_in[14];
  const float* efc1_b = (const float*)d_in[15];
  const float* efc2_w = (const float*)d_in[16];
  const float* efc2_b = (const float*)d_in[17];
  float* out = (float*)d_out;

  const int E = in_sizes[1];

  float* ws   = (float*)d_ws;
  int*  cnt   = (int*)(ws + OFF_CNT);
  int*  icnt  = (int*)(ws + OFF_ICNT);
  int*  ucnt  = (int*)(ws + OFF_UCNT);
  int*  icur  = (int*)(ws + OFF_ICUR);
  int*  ucur  = (int*)(ws + OFF_UCUR);
  int*  icsr  = (int*)(ws + OFF_ICSR);
  int*  ucsr  = (int*)(ws + OFF_UCSR);
  uint* Wc    = (uint*)(ws + OFF_WC);
  uint* acc   = (uint*)(ws + OFF_ACC);
  uint* mean  = (uint*)(ws + OFF_MEAN);
  float* score = ws + OFF_SCORE;

  hipMemsetAsync(d_ws, 0, (size_t)ZERO_ELEMS * sizeof(float), stream);

  int countBlocks = (E + 255) / 256;
  k_initcomb<<<COMBINE_BLOCKS + countBlocks, 256, 0, stream>>>(
      basis, comp, Wc, ei, et, E, cnt, icnt, ucnt);
  k_scan<<<2, 1024, 0, stream>>>(icnt, ucnt, icur, ucur);
  k_fill<<<countBlocks, 256, 0, stream>>>(ei, et, E, icur, ucur, icsr, ucsr);
  k_useragg<<<N_USERS / 4, 256, 0, stream>>>(ucnt, ucur, ucsr, cnt, Wc, root, acc);
  k_itemagg<<<N_ITEMS / 4, 256, 0, stream>>>(icnt, icur, icsr, acc, bias, attn_a,
                                             attn_b, mean, score);
  k_batch2<<<BATCH / 2, 256, 0, stream>>>(ctx0, ctx1, mean, score, fc1_w, fc1_b,
                                          fc2_w, fc2_b, efc1_w, efc1_b, efc2_w,
                                          efc2_b, out);
}